// Round 2
// baseline (779.798 us; speedup 1.0000x reference)
//
#include <hip/hip_runtime.h>

// Problem constants (from reference)
#define BN   8192
#define TN   128
#define SDIM 6
#define NIV  6
#define HIDN 256
#define DTC  0.01f
// IN_DIM = 50: [ e(6) | e_dot(6) | xi(6) | mf(32) ], mf constant over t per b.

// One wave (64 lanes) per batch element b. Lane L owns hidden units
// j = u*64 + L, u = 0..3. Weights pinned in VGPRs via empty asm so the
// compiler cannot rematerialize their loads inside the t-loop (round-1
// showed VGPR_Count=120 << live set => per-step weight reloads).
#define KEEP(x) asm volatile("" : "+v"(x))

__global__ __launch_bounds__(256, 2)
void visco_kernel(const float* __restrict__ e,    const float* __restrict__ ed,
                  const float* __restrict__ Earr, const float* __restrict__ nuarr,
                  const float* __restrict__ We,   const float* __restrict__ be,
                  const float* __restrict__ Wn,   const float* __restrict__ bn,
                  const float* __restrict__ Wen1, const float* __restrict__ ben1,
                  const float* __restrict__ Wen2, const float* __restrict__ ben2,
                  const float* __restrict__ Wd1,  const float* __restrict__ bd1,
                  const float* __restrict__ Wd2,  const float* __restrict__ bd2,
                  float* __restrict__ out)
{
    const int lane = threadIdx.x & 63;
    const int wv   = threadIdx.x >> 6;
    const int b    = (blockIdx.x << 2) + wv;   // grid = 2048 blocks * 4 waves = 8192

    // ---- per-lane weight registers ----
    float wE[2][4][6];   // layer-1 weights, e-part   (mlp 0 = encoder, 1 = kinetics)
    float wD[2][4][6];   // layer-1 weights, e_dot-part
    float wX[2][4][6];   // layer-1 weights, xi-part
    float cst[2][4];     // bias + (mf @ W1[18:50]) folded constant
    float w2s[4];        // Wen2[j]
    float w2k[4][6];     // Wd2[j][i]

    const float Eb  = Earr[b];
    const float nub = nuarr[b];

    #pragma unroll
    for (int u = 0; u < 4; ++u) {
        const int j = (u << 6) + lane;
        #pragma unroll
        for (int k = 0; k < 6; ++k) {
            wE[0][u][k] = Wen1[(k     ) * HIDN + j];
            wD[0][u][k] = Wen1[(6  + k) * HIDN + j];
            wX[0][u][k] = Wen1[(12 + k) * HIDN + j];
            wE[1][u][k] = Wd1 [(k     ) * HIDN + j];
            wD[1][u][k] = Wd1 [(6  + k) * HIDN + j];
            wX[1][u][k] = Wd1 [(12 + k) * HIDN + j];
        }
        float c0 = ben1[j];
        float c1 = bd1[j];
        #pragma unroll
        for (int k = 0; k < 16; ++k) {           // mf[0:16] = E*We + be
            const float m = fmaf(Eb, We[k], be[k]);
            c0 = fmaf(m, Wen1[(18 + k) * HIDN + j], c0);
            c1 = fmaf(m, Wd1 [(18 + k) * HIDN + j], c1);
        }
        #pragma unroll
        for (int k = 0; k < 16; ++k) {           // mf[16:32] = nu*Wn + bn
            const float m = fmaf(nub, Wn[k], bn[k]);
            c0 = fmaf(m, Wen1[(34 + k) * HIDN + j], c0);
            c1 = fmaf(m, Wd1 [(34 + k) * HIDN + j], c1);
        }
        cst[0][u] = c0;
        cst[1][u] = c1;
        w2s[u] = Wen2[j];
        #pragma unroll
        for (int i = 0; i < 6; ++i) w2k[u][i] = Wd2[j * 6 + i];
    }

    // ---- pin every loop-invariant value into a VGPR (blocks remat) ----
    #pragma unroll
    for (int u = 0; u < 4; ++u) {
        #pragma unroll
        for (int k = 0; k < 6; ++k) {
            KEEP(wE[0][u][k]); KEEP(wE[1][u][k]);
            KEEP(wD[0][u][k]); KEEP(wD[1][u][k]);
            KEEP(wX[0][u][k]); KEEP(wX[1][u][k]);
            KEEP(w2k[u][k]);
        }
        KEEP(cst[0][u]); KEEP(cst[1][u]); KEEP(w2s[u]);
    }

    const float ben2v = ben2[0];
    float xb[6];                      // DT * bd2[i], folded into Euler update
    #pragma unroll
    for (int i = 0; i < 6; ++i) { xb[i] = DTC * bd2[i]; KEEP(xb[i]); }

    // ---- state + streams ----
    float xi0 = 0.f, xi1 = 0.f, xi2 = 0.f, xi3 = 0.f, xi4 = 0.f, xi5 = 0.f;

    const float2* ep = (const float2*)(e  + (size_t)b * (TN * 6));
    const float2* dp = (const float2*)(ed + (size_t)b * (TN * 6));
    float* outS = out + (size_t)b * TN;                            // stress [B,T]
    float* outX = out + (size_t)BN * TN + (size_t)b * (TN * 6);    // xi_all [B,T,6]

    // prefetch t=0
    float2 e0 = ep[0], e1 = ep[1], e2 = ep[2];
    float2 d0 = dp[0], d1 = dp[1], d2 = dp[2];

    for (int t = 0; t < TN; ++t) {
        const float ev0 = e0.x, ev1 = e0.y, ev2 = e1.x, ev3 = e1.y, ev4 = e2.x, ev5 = e2.y;
        const float dv0 = d0.x, dv1 = d0.y, dv2 = d1.x, dv3 = d1.y, dv4 = d2.x, dv5 = d2.y;

        // prefetch t+1 (clamped; independent of the xi chain)
        const int tn = (t + 1 < TN) ? t + 1 : t;
        e0 = ep[tn * 3 + 0]; e1 = ep[tn * 3 + 1]; e2 = ep[tn * 3 + 2];
        d0 = dp[tn * 3 + 0]; d1 = dp[tn * 3 + 1]; d2 = dp[tn * 3 + 2];

        float ps  = 0.f;
        float pk0 = 0.f, pk1 = 0.f, pk2 = 0.f, pk3 = 0.f, pk4 = 0.f, pk5 = 0.f;

        #pragma unroll
        for (int u = 0; u < 4; ++u) {
            float h = cst[0][u];
            float g = cst[1][u];
            h = fmaf(ev0, wE[0][u][0], h);  g = fmaf(ev0, wE[1][u][0], g);
            h = fmaf(ev1, wE[0][u][1], h);  g = fmaf(ev1, wE[1][u][1], g);
            h = fmaf(ev2, wE[0][u][2], h);  g = fmaf(ev2, wE[1][u][2], g);
            h = fmaf(ev3, wE[0][u][3], h);  g = fmaf(ev3, wE[1][u][3], g);
            h = fmaf(ev4, wE[0][u][4], h);  g = fmaf(ev4, wE[1][u][4], g);
            h = fmaf(ev5, wE[0][u][5], h);  g = fmaf(ev5, wE[1][u][5], g);
            h = fmaf(dv0, wD[0][u][0], h);  g = fmaf(dv0, wD[1][u][0], g);
            h = fmaf(dv1, wD[0][u][1], h);  g = fmaf(dv1, wD[1][u][1], g);
            h = fmaf(dv2, wD[0][u][2], h);  g = fmaf(dv2, wD[1][u][2], g);
            h = fmaf(dv3, wD[0][u][3], h);  g = fmaf(dv3, wD[1][u][3], g);
            h = fmaf(dv4, wD[0][u][4], h);  g = fmaf(dv4, wD[1][u][4], g);
            h = fmaf(dv5, wD[0][u][5], h);  g = fmaf(dv5, wD[1][u][5], g);
            h = fmaf(xi0, wX[0][u][0], h);  g = fmaf(xi0, wX[1][u][0], g);
            h = fmaf(xi1, wX[0][u][1], h);  g = fmaf(xi1, wX[1][u][1], g);
            h = fmaf(xi2, wX[0][u][2], h);  g = fmaf(xi2, wX[1][u][2], g);
            h = fmaf(xi3, wX[0][u][3], h);  g = fmaf(xi3, wX[1][u][3], g);
            h = fmaf(xi4, wX[0][u][4], h);  g = fmaf(xi4, wX[1][u][4], g);
            h = fmaf(xi5, wX[0][u][5], h);  g = fmaf(xi5, wX[1][u][5], g);
            h = fmaxf(h, 0.f);
            g = fmaxf(g, 0.f);
            ps  = fmaf(h, w2s[u],    ps);
            pk0 = fmaf(g, w2k[u][0], pk0);
            pk1 = fmaf(g, w2k[u][1], pk1);
            pk2 = fmaf(g, w2k[u][2], pk2);
            pk3 = fmaf(g, w2k[u][3], pk3);
            pk4 = fmaf(g, w2k[u][4], pk4);
            pk5 = fmaf(g, w2k[u][5], pk5);
        }

        // 64-lane butterfly reduction of 7 values (all lanes end with totals)
        #pragma unroll
        for (int m = 1; m < 64; m <<= 1) {
            ps  += __shfl_xor(ps,  m);
            pk0 += __shfl_xor(pk0, m);
            pk1 += __shfl_xor(pk1, m);
            pk2 += __shfl_xor(pk2, m);
            pk3 += __shfl_xor(pk3, m);
            pk4 += __shfl_xor(pk4, m);
            pk5 += __shfl_xor(pk5, m);
        }

        // emit xi BEFORE update, stress
        const float xw = (lane == 0) ? xi0 :
                         (lane == 1) ? xi1 :
                         (lane == 2) ? xi2 :
                         (lane == 3) ? xi3 :
                         (lane == 4) ? xi4 : xi5;
        if (lane < 6)  outX[t * 6 + lane] = xw;
        if (lane == 6) outS[t] = ps + ben2v;

        // explicit Euler update (uniform across lanes)
        xi0 = fmaf(DTC, pk0, xi0 + xb[0]);
        xi1 = fmaf(DTC, pk1, xi1 + xb[1]);
        xi2 = fmaf(DTC, pk2, xi2 + xb[2]);
        xi3 = fmaf(DTC, pk3, xi3 + xb[3]);
        xi4 = fmaf(DTC, pk4, xi4 + xb[4]);
        xi5 = fmaf(DTC, pk5, xi5 + xb[5]);
    }
}

extern "C" void kernel_launch(void* const* d_in, const int* in_sizes, int n_in,
                              void* d_out, int out_size, void* d_ws, size_t ws_size,
                              hipStream_t stream) {
    const float* e    = (const float*)d_in[0];
    const float* ed   = (const float*)d_in[1];
    const float* E    = (const float*)d_in[2];
    const float* nu   = (const float*)d_in[3];
    const float* We   = (const float*)d_in[4];
    const float* be   = (const float*)d_in[5];
    const float* Wn   = (const float*)d_in[6];
    const float* bn   = (const float*)d_in[7];
    const float* Wen1 = (const float*)d_in[8];
    const float* ben1 = (const float*)d_in[9];
    const float* Wen2 = (const float*)d_in[10];
    const float* ben2 = (const float*)d_in[11];
    const float* Wd1  = (const float*)d_in[12];
    const float* bd1  = (const float*)d_in[13];
    const float* Wd2  = (const float*)d_in[14];
    const float* bd2  = (const float*)d_in[15];
    float* out = (float*)d_out;

    dim3 grid(BN / 4);   // 4 waves (4 batch elems) per 256-thread block
    dim3 block(256);
    visco_kernel<<<grid, block, 0, stream>>>(e, ed, E, nu, We, be, Wn, bn,
                                             Wen1, ben1, Wen2, ben2,
                                             Wd1, bd1, Wd2, bd2, out);
}

// Round 3
// 631.516 us; speedup vs baseline: 1.2348x; 1.2348x over previous
//
#include <hip/hip_runtime.h>

// Problem constants (from reference)
#define BN   8192
#define TN   128
#define HIDN 256
#define DTC  0.01f
// IN_DIM = 50: [ e(6) | e_dot(6) | xi(6) | mf(32) ], mf constant over t per b.

typedef float v2f __attribute__((ext_vector_type(2)));

// ---- DPP wave-64 sum: 6 dpp-adds, total lands in lane 63, then readlane ----
// update_dpp(old=0, src, ctrl, row_mask, bank_mask, bound_ctrl=true):
// masked-off / out-of-range lanes contribute 0, so v += dpp(v) is safe.
#define DPP_ADD(v, ctrl, rmask)                                                 \
    v += __int_as_float(__builtin_amdgcn_update_dpp(                            \
            0, __float_as_int(v), ctrl, rmask, 0xf, true))

#define WAVE_SUM(v) do {                                                        \
    DPP_ADD(v, 0x111, 0xf);  /* row_shr:1  */                                   \
    DPP_ADD(v, 0x112, 0xf);  /* row_shr:2  */                                   \
    DPP_ADD(v, 0x114, 0xf);  /* row_shr:4  */                                   \
    DPP_ADD(v, 0x118, 0xf);  /* row_shr:8  -> lane 16r+15 = row sum */          \
    DPP_ADD(v, 0x142, 0xa);  /* row_bcast:15 -> lane31=sum(0..31), 63=sum(32..63) */ \
    DPP_ADD(v, 0x143, 0xc);  /* row_bcast:31 -> lane63=sum(0..63) */            \
} while (0)

#define LANE_SUM(v) __int_as_float(__builtin_amdgcn_readlane(__float_as_int(v), 63))

// One wave (64 lanes) per batch element b. Lane L owns hidden units
// j = u*64 + L, u = 0..3, for BOTH MLPs (m=0 encoder, m=1 kinetics).
// Layer-1 runs K-packed: x pairs (x[2k],x[2k+1]) * weight pairs via
// v_pk_fma_f32 (2 FMA/issue). Reductions are DPP (no LDS, no ds_swizzle).
__global__ __launch_bounds__(256, 2)
void visco_kernel(const float* __restrict__ e,    const float* __restrict__ ed,
                  const float* __restrict__ Earr, const float* __restrict__ nuarr,
                  const float* __restrict__ We,   const float* __restrict__ be,
                  const float* __restrict__ Wn,   const float* __restrict__ bn,
                  const float* __restrict__ Wen1, const float* __restrict__ ben1,
                  const float* __restrict__ Wen2, const float* __restrict__ ben2,
                  const float* __restrict__ Wd1,  const float* __restrict__ bd1,
                  const float* __restrict__ Wd2,  const float* __restrict__ bd2,
                  float* __restrict__ out)
{
    const int lane = threadIdx.x & 63;
    const int wv   = threadIdx.x >> 6;
    const int b    = (blockIdx.x << 2) + wv;   // 2048 blocks * 4 waves = 8192

    // ---- per-lane weight registers (K-pair layout) ----
    // wP[m][u][kk] = (W1[2kk][j], W1[2kk+1][j]), kk=0..8 covering rows 0..17
    v2f   wP[2][4][9];
    float cst[2][4];     // bias + (mf @ W1[18:50]) folded constant
    float w2s[4];        // Wen2[j]
    float w2k[4][6];     // Wd2[j][i]

    const float Eb  = Earr[b];
    const float nub = nuarr[b];

    #pragma unroll
    for (int u = 0; u < 4; ++u) {
        const int j = (u << 6) + lane;
        #pragma unroll
        for (int kk = 0; kk < 9; ++kk) {
            wP[0][u][kk] = v2f{Wen1[(2 * kk) * HIDN + j], Wen1[(2 * kk + 1) * HIDN + j]};
            wP[1][u][kk] = v2f{Wd1 [(2 * kk) * HIDN + j], Wd1 [(2 * kk + 1) * HIDN + j]};
        }
        float c0 = ben1[j];
        float c1 = bd1[j];
        #pragma unroll
        for (int k = 0; k < 16; ++k) {           // mf[0:16] = E*We + be
            const float m = fmaf(Eb, We[k], be[k]);
            c0 = fmaf(m, Wen1[(18 + k) * HIDN + j], c0);
            c1 = fmaf(m, Wd1 [(18 + k) * HIDN + j], c1);
        }
        #pragma unroll
        for (int k = 0; k < 16; ++k) {           // mf[16:32] = nu*Wn + bn
            const float m = fmaf(nub, Wn[k], bn[k]);
            c0 = fmaf(m, Wen1[(34 + k) * HIDN + j], c0);
            c1 = fmaf(m, Wd1 [(34 + k) * HIDN + j], c1);
        }
        cst[0][u] = c0;
        cst[1][u] = c1;
        w2s[u] = Wen2[j];
        #pragma unroll
        for (int i = 0; i < 6; ++i) w2k[u][i] = Wd2[j * 6 + i];
    }

    const float ben2v = ben2[0];
    float bd2v[6];
    #pragma unroll
    for (int i = 0; i < 6; ++i) bd2v[i] = bd2[i];

    // ---- state (uniform across lanes) + streams ----
    v2f xi01 = v2f{0.f, 0.f}, xi23 = v2f{0.f, 0.f}, xi45 = v2f{0.f, 0.f};

    const v2f* ep = (const v2f*)(e  + (size_t)b * (TN * 6));
    const v2f* dp = (const v2f*)(ed + (size_t)b * (TN * 6));
    float* outS = out + (size_t)b * TN;                            // stress [B,T]
    float* outX = out + (size_t)BN * TN + (size_t)b * (TN * 6);    // xi_all [B,T,6]

    // prefetch t=0
    v2f e0 = ep[0], e1 = ep[1], e2 = ep[2];
    v2f d0 = dp[0], d1 = dp[1], d2 = dp[2];

    for (int t = 0; t < TN; ++t) {
        const v2f x0 = e0, x1 = e1, x2v = e2;   // e pairs
        const v2f x3 = d0, x4 = d1, x5 = d2;    // e_dot pairs

        // prefetch t+1 (clamped; independent of the xi chain)
        const int tn = (t + 1 < TN) ? t + 1 : t;
        e0 = ep[tn * 3 + 0]; e1 = ep[tn * 3 + 1]; e2 = ep[tn * 3 + 2];
        d0 = dp[tn * 3 + 0]; d1 = dp[tn * 3 + 1]; d2 = dp[tn * 3 + 2];

        float ps  = 0.f;
        float pk0 = 0.f, pk1 = 0.f, pk2 = 0.f, pk3 = 0.f, pk4 = 0.f, pk5 = 0.f;

        #pragma unroll
        for (int u = 0; u < 4; ++u) {
            // packed partial sums; .x holds even-k terms (+cst), .y odd-k terms
            v2f hp = v2f{cst[0][u], 0.f};
            v2f gp = v2f{cst[1][u], 0.f};
            hp = __builtin_elementwise_fma(x0,   wP[0][u][0], hp);
            gp = __builtin_elementwise_fma(x0,   wP[1][u][0], gp);
            hp = __builtin_elementwise_fma(x1,   wP[0][u][1], hp);
            gp = __builtin_elementwise_fma(x1,   wP[1][u][1], gp);
            hp = __builtin_elementwise_fma(x2v,  wP[0][u][2], hp);
            gp = __builtin_elementwise_fma(x2v,  wP[1][u][2], gp);
            hp = __builtin_elementwise_fma(x3,   wP[0][u][3], hp);
            gp = __builtin_elementwise_fma(x3,   wP[1][u][3], gp);
            hp = __builtin_elementwise_fma(x4,   wP[0][u][4], hp);
            gp = __builtin_elementwise_fma(x4,   wP[1][u][4], gp);
            hp = __builtin_elementwise_fma(x5,   wP[0][u][5], hp);
            gp = __builtin_elementwise_fma(x5,   wP[1][u][5], gp);
            hp = __builtin_elementwise_fma(xi01, wP[0][u][6], hp);
            gp = __builtin_elementwise_fma(xi01, wP[1][u][6], gp);
            hp = __builtin_elementwise_fma(xi23, wP[0][u][7], hp);
            gp = __builtin_elementwise_fma(xi23, wP[1][u][7], gp);
            hp = __builtin_elementwise_fma(xi45, wP[0][u][8], hp);
            gp = __builtin_elementwise_fma(xi45, wP[1][u][8], gp);

            const float h = fmaxf(hp.x + hp.y, 0.f);
            const float g = fmaxf(gp.x + gp.y, 0.f);
            ps  = fmaf(h, w2s[u],    ps);
            pk0 = fmaf(g, w2k[u][0], pk0);
            pk1 = fmaf(g, w2k[u][1], pk1);
            pk2 = fmaf(g, w2k[u][2], pk2);
            pk3 = fmaf(g, w2k[u][3], pk3);
            pk4 = fmaf(g, w2k[u][4], pk4);
            pk5 = fmaf(g, w2k[u][5], pk5);
        }

        // DPP wave sums (no LDS); totals -> SGPRs via readlane 63
        WAVE_SUM(ps);
        WAVE_SUM(pk0); WAVE_SUM(pk1); WAVE_SUM(pk2);
        WAVE_SUM(pk3); WAVE_SUM(pk4); WAVE_SUM(pk5);
        const float sS  = LANE_SUM(ps);
        const float s0  = LANE_SUM(pk0);
        const float s1  = LANE_SUM(pk1);
        const float s2  = LANE_SUM(pk2);
        const float s3  = LANE_SUM(pk3);
        const float s4  = LANE_SUM(pk4);
        const float s5  = LANE_SUM(pk5);

        // emit xi BEFORE update, stress
        const float xw = (lane == 0) ? xi01.x :
                         (lane == 1) ? xi01.y :
                         (lane == 2) ? xi23.x :
                         (lane == 3) ? xi23.y :
                         (lane == 4) ? xi45.x : xi45.y;
        if (lane < 6)  outX[t * 6 + lane] = xw;
        if (lane == 6) outS[t] = sS + ben2v;

        // explicit Euler update: xi += DT * (pk_sum + bd2)   (reference order)
        xi01.x = fmaf(DTC, s0 + bd2v[0], xi01.x);
        xi01.y = fmaf(DTC, s1 + bd2v[1], xi01.y);
        xi23.x = fmaf(DTC, s2 + bd2v[2], xi23.x);
        xi23.y = fmaf(DTC, s3 + bd2v[3], xi23.y);
        xi45.x = fmaf(DTC, s4 + bd2v[4], xi45.x);
        xi45.y = fmaf(DTC, s5 + bd2v[5], xi45.y);
    }
}

extern "C" void kernel_launch(void* const* d_in, const int* in_sizes, int n_in,
                              void* d_out, int out_size, void* d_ws, size_t ws_size,
                              hipStream_t stream) {
    const float* e    = (const float*)d_in[0];
    const float* ed   = (const float*)d_in[1];
    const float* E    = (const float*)d_in[2];
    const float* nu   = (const float*)d_in[3];
    const float* We   = (const float*)d_in[4];
    const float* be   = (const float*)d_in[5];
    const float* Wn   = (const float*)d_in[6];
    const float* bn   = (const float*)d_in[7];
    const float* Wen1 = (const float*)d_in[8];
    const float* ben1 = (const float*)d_in[9];
    const float* Wen2 = (const float*)d_in[10];
    const float* ben2 = (const float*)d_in[11];
    const float* Wd1  = (const float*)d_in[12];
    const float* bd1  = (const float*)d_in[13];
    const float* Wd2  = (const float*)d_in[14];
    const float* bd2  = (const float*)d_in[15];
    float* out = (float*)d_out;

    dim3 grid(BN / 4);   // 4 waves (4 batch elems) per 256-thread block
    dim3 block(256);
    visco_kernel<<<grid, block, 0, stream>>>(e, ed, E, nu, We, be, Wn, bn,
                                             Wen1, ben1, Wen2, ben2,
                                             Wd1, bd1, Wd2, bd2, out);
}

// Round 5
// 572.585 us; speedup vs baseline: 1.3619x; 1.1029x over previous
//
#include <hip/hip_runtime.h>

// Problem constants (from reference)
#define BN   8192
#define TN   128
#define HIDN 256
#define DTC  0.01f
// IN_DIM = 50: [ e(6) | e_dot(6) | xi(6) | mf(32) ], mf constant over t per b.

typedef float v2f __attribute__((ext_vector_type(2)));

// ---- DPP wave-64 sum: 6 dpp-adds, total lands in lane 63, then readlane ----
#define DPP_ADD(v, ctrl, rmask)                                                 \
    v += __int_as_float(__builtin_amdgcn_update_dpp(                            \
            0, __float_as_int(v), ctrl, rmask, 0xf, true))

#define WAVE_SUM(v) do {                                                        \
    DPP_ADD(v, 0x111, 0xf);  /* row_shr:1  */                                   \
    DPP_ADD(v, 0x112, 0xf);  /* row_shr:2  */                                   \
    DPP_ADD(v, 0x114, 0xf);  /* row_shr:4  */                                   \
    DPP_ADD(v, 0x118, 0xf);  /* row_shr:8  */                                   \
    DPP_ADD(v, 0x142, 0xa);  /* row_bcast:15 */                                 \
    DPP_ADD(v, 0x143, 0xc);  /* row_bcast:31 -> lane63 = sum(0..63) */          \
} while (0)

#define LANE_SUM(v)  __int_as_float(__builtin_amdgcn_readlane(__float_as_int(v), 63))
#define RDLANE(v, l) __int_as_float(__builtin_amdgcn_readlane(__float_as_int(v), (l)))
#define KEEP(x) asm volatile("" : "+v"(x))

// One wave per batch element b. Lane L owns hidden units j = u*64+L, u=0..3,
// for BOTH MLPs. Layer-1 K-packed via v_pk_fma_f32. Inputs for 64 steps are
// staged per-lane (lane L holds step L's 12 features) and broadcast per step
// with v_readlane(uniform t) -> zero per-step memory traffic.
// __launch_bounds__(256,1): 512-reg budget so the ~240-value live set stays
// in arch VGPRs (no AGPR parking / copy tax); occupancy unchanged at 2/SIMD.
__global__ __launch_bounds__(256, 1)
void visco_kernel(const float* __restrict__ e,    const float* __restrict__ ed,
                  const float* __restrict__ Earr, const float* __restrict__ nuarr,
                  const float* __restrict__ We,   const float* __restrict__ be,
                  const float* __restrict__ Wn,   const float* __restrict__ bn,
                  const float* __restrict__ Wen1, const float* __restrict__ ben1,
                  const float* __restrict__ Wen2, const float* __restrict__ ben2,
                  const float* __restrict__ Wd1,  const float* __restrict__ bd1,
                  const float* __restrict__ Wd2,  const float* __restrict__ bd2,
                  float* __restrict__ out)
{
    const int lane = threadIdx.x & 63;
    const int wv   = threadIdx.x >> 6;
    const int b    = (blockIdx.x << 2) + wv;   // 2048 blocks * 4 waves = 8192

    // ---- per-lane weight registers (K-pair layout) ----
    v2f   wP[2][4][9];   // wP[m][u][kk] = (W1[2kk][j], W1[2kk+1][j])
    v2f   cstP[2][4];    // {bias + mf-fold, 0} — accumulator seed (no movs/step)
    float w2s[4];        // Wen2[j]
    float w2k[4][6];     // Wd2[j][i]

    const float Eb  = Earr[b];
    const float nub = nuarr[b];

    #pragma unroll
    for (int u = 0; u < 4; ++u) {
        const int j = (u << 6) + lane;
        #pragma unroll
        for (int kk = 0; kk < 9; ++kk) {
            wP[0][u][kk] = v2f{Wen1[(2 * kk) * HIDN + j], Wen1[(2 * kk + 1) * HIDN + j]};
            wP[1][u][kk] = v2f{Wd1 [(2 * kk) * HIDN + j], Wd1 [(2 * kk + 1) * HIDN + j]};
        }
        float c0 = ben1[j];
        float c1 = bd1[j];
        #pragma unroll
        for (int k = 0; k < 16; ++k) {           // mf[0:16] = E*We + be
            const float m = fmaf(Eb, We[k], be[k]);
            c0 = fmaf(m, Wen1[(18 + k) * HIDN + j], c0);
            c1 = fmaf(m, Wd1 [(18 + k) * HIDN + j], c1);
        }
        #pragma unroll
        for (int k = 0; k < 16; ++k) {           // mf[16:32] = nu*Wn + bn
            const float m = fmaf(nub, Wn[k], bn[k]);
            c0 = fmaf(m, Wen1[(34 + k) * HIDN + j], c0);
            c1 = fmaf(m, Wd1 [(34 + k) * HIDN + j], c1);
        }
        cstP[0][u] = v2f{c0, 0.f};
        cstP[1][u] = v2f{c1, 0.f};
        w2s[u] = Wen2[j];
        #pragma unroll
        for (int i = 0; i < 6; ++i) w2k[u][i] = Wd2[j * 6 + i];
    }

    // pin loop-invariants (with the 512-reg budget these stay arch-VGPR)
    #pragma unroll
    for (int u = 0; u < 4; ++u) {
        #pragma unroll
        for (int kk = 0; kk < 9; ++kk) {
            KEEP(wP[0][u][kk].x); KEEP(wP[0][u][kk].y);
            KEEP(wP[1][u][kk].x); KEEP(wP[1][u][kk].y);
        }
        #pragma unroll
        for (int i = 0; i < 6; ++i) KEEP(w2k[u][i]);
        KEEP(cstP[0][u].x); KEEP(cstP[1][u].x); KEEP(w2s[u]);
    }

    const float ben2v = ben2[0];
    float bd2v[6];
    #pragma unroll
    for (int i = 0; i < 6; ++i) { bd2v[i] = bd2[i]; KEEP(bd2v[i]); }

    // ---- state (uniform across lanes) + output streams ----
    v2f xi01 = v2f{0.f, 0.f}, xi23 = v2f{0.f, 0.f}, xi45 = v2f{0.f, 0.f};

    const float* eb = e  + (size_t)b * (TN * 6);
    const float* db = ed + (size_t)b * (TN * 6);
    float* outS = out + (size_t)b * TN;                            // stress [B,T]
    float* outX = out + (size_t)BN * TN + (size_t)b * (TN * 6);    // xi_all [B,T,6]

    for (int half = 0; half < 2; ++half) {
        // stage 64 steps: lane L holds features of step (half*64 + L)
        float sE[6], sD[6];
        const int base = ((half << 6) + lane) * 6;
        #pragma unroll
        for (int r = 0; r < 6; ++r) { sE[r] = eb[base + r]; sD[r] = db[base + r]; }

        #pragma unroll 2
        for (int t2 = 0; t2 < 64; ++t2) {
            const int t = (half << 6) + t2;

            // broadcast step t's inputs from lane t2 (pure VALU, no memory)
            const v2f x0 = v2f{RDLANE(sE[0], t2), RDLANE(sE[1], t2)};
            const v2f x1 = v2f{RDLANE(sE[2], t2), RDLANE(sE[3], t2)};
            const v2f x2 = v2f{RDLANE(sE[4], t2), RDLANE(sE[5], t2)};
            const v2f x3 = v2f{RDLANE(sD[0], t2), RDLANE(sD[1], t2)};
            const v2f x4 = v2f{RDLANE(sD[2], t2), RDLANE(sD[3], t2)};
            const v2f x5 = v2f{RDLANE(sD[4], t2), RDLANE(sD[5], t2)};

            float ps  = 0.f;
            float pk0 = 0.f, pk1 = 0.f, pk2 = 0.f, pk3 = 0.f, pk4 = 0.f, pk5 = 0.f;

            #pragma unroll
            for (int u = 0; u < 4; ++u) {
                v2f hp = __builtin_elementwise_fma(x0, wP[0][u][0], cstP[0][u]);
                v2f gp = __builtin_elementwise_fma(x0, wP[1][u][0], cstP[1][u]);
                hp = __builtin_elementwise_fma(x1,   wP[0][u][1], hp);
                gp = __builtin_elementwise_fma(x1,   wP[1][u][1], gp);
                hp = __builtin_elementwise_fma(x2,   wP[0][u][2], hp);
                gp = __builtin_elementwise_fma(x2,   wP[1][u][2], gp);
                hp = __builtin_elementwise_fma(x3,   wP[0][u][3], hp);
                gp = __builtin_elementwise_fma(x3,   wP[1][u][3], gp);
                hp = __builtin_elementwise_fma(x4,   wP[0][u][4], hp);
                gp = __builtin_elementwise_fma(x4,   wP[1][u][4], gp);
                hp = __builtin_elementwise_fma(x5,   wP[0][u][5], hp);
                gp = __builtin_elementwise_fma(x5,   wP[1][u][5], gp);
                hp = __builtin_elementwise_fma(xi01, wP[0][u][6], hp);
                gp = __builtin_elementwise_fma(xi01, wP[1][u][6], gp);
                hp = __builtin_elementwise_fma(xi23, wP[0][u][7], hp);
                gp = __builtin_elementwise_fma(xi23, wP[1][u][7], gp);
                hp = __builtin_elementwise_fma(xi45, wP[0][u][8], hp);
                gp = __builtin_elementwise_fma(xi45, wP[1][u][8], gp);

                const float h = fmaxf(hp.x + hp.y, 0.f);
                const float g = fmaxf(gp.x + gp.y, 0.f);
                ps  = fmaf(h, w2s[u],    ps);
                pk0 = fmaf(g, w2k[u][0], pk0);
                pk1 = fmaf(g, w2k[u][1], pk1);
                pk2 = fmaf(g, w2k[u][2], pk2);
                pk3 = fmaf(g, w2k[u][3], pk3);
                pk4 = fmaf(g, w2k[u][4], pk4);
                pk5 = fmaf(g, w2k[u][5], pk5);
            }

            // DPP wave sums; totals -> uniform via readlane 63
            WAVE_SUM(ps);
            WAVE_SUM(pk0); WAVE_SUM(pk1); WAVE_SUM(pk2);
            WAVE_SUM(pk3); WAVE_SUM(pk4); WAVE_SUM(pk5);
            const float sS = LANE_SUM(ps);
            const float s0 = LANE_SUM(pk0);
            const float s1 = LANE_SUM(pk1);
            const float s2 = LANE_SUM(pk2);
            const float s3 = LANE_SUM(pk3);
            const float s4 = LANE_SUM(pk4);
            const float s5 = LANE_SUM(pk5);

            // emit xi BEFORE update, stress
            const float xw = (lane == 0) ? xi01.x :
                             (lane == 1) ? xi01.y :
                             (lane == 2) ? xi23.x :
                             (lane == 3) ? xi23.y :
                             (lane == 4) ? xi45.x : xi45.y;
            if (lane < 6)  outX[t * 6 + lane] = xw;
            if (lane == 6) outS[t] = sS + ben2v;

            // explicit Euler: xi += DT * (kin_sum + bd2)   (reference order)
            xi01.x = fmaf(DTC, s0 + bd2v[0], xi01.x);
            xi01.y = fmaf(DTC, s1 + bd2v[1], xi01.y);
            xi23.x = fmaf(DTC, s2 + bd2v[2], xi23.x);
            xi23.y = fmaf(DTC, s3 + bd2v[3], xi23.y);
            xi45.x = fmaf(DTC, s4 + bd2v[4], xi45.x);
            xi45.y = fmaf(DTC, s5 + bd2v[5], xi45.y);
        }
    }
}

extern "C" void kernel_launch(void* const* d_in, const int* in_sizes, int n_in,
                              void* d_out, int out_size, void* d_ws, size_t ws_size,
                              hipStream_t stream) {
    const float* e    = (const float*)d_in[0];
    const float* ed   = (const float*)d_in[1];
    const float* E    = (const float*)d_in[2];
    const float* nu   = (const float*)d_in[3];
    const float* We   = (const float*)d_in[4];
    const float* be   = (const float*)d_in[5];
    const float* Wn   = (const float*)d_in[6];
    const float* bn   = (const float*)d_in[7];
    const float* Wen1 = (const float*)d_in[8];
    const float* ben1 = (const float*)d_in[9];
    const float* Wen2 = (const float*)d_in[10];
    const float* ben2 = (const float*)d_in[11];
    const float* Wd1  = (const float*)d_in[12];
    const float* bd1  = (const float*)d_in[13];
    const float* Wd2  = (const float*)d_in[14];
    const float* bd2  = (const float*)d_in[15];
    float* out = (float*)d_out;

    dim3 grid(BN / 4);   // 4 waves (4 batch elems) per 256-thread block
    dim3 block(256);
    visco_kernel<<<grid, block, 0, stream>>>(e, ed, E, nu, We, be, Wn, bn,
                                             Wen1, ben1, Wen2, ben2,
                                             Wd1, bd1, Wd2, bd2, out);
}

// Round 6
// 535.506 us; speedup vs baseline: 1.4562x; 1.0692x over previous
//
#include <hip/hip_runtime.h>

// Problem constants (from reference)
#define BN   8192
#define TN   128
#define HIDN 256
#define DTC  0.01f
// IN_DIM = 50: [ e(6) | e_dot(6) | xi(6) | mf(32) ], mf constant over t per b.

typedef float v2f __attribute__((ext_vector_type(2)));

// ---- forced VOP3P packed fp32 FMA (full-rate path; "v" pins arch VGPRs) ----
// d += a * w   (element-wise on 2xf32)
#define PK_FMA(d, a, w) \
    asm("v_pk_fma_f32 %0, %1, %2, %0" : "+v"(d) : "v"(a), "v"(w))
// d = a * w + c  (seed from c without a copy)
#define PK_FMA3(d, a, w, c) \
    asm("v_pk_fma_f32 %0, %1, %2, %3" : "=v"(d) : "v"(a), "v"(w), "v"(c))
// scalar: d += a * w
#define SFMA(d, a, w) \
    asm("v_fma_f32 %0, %1, %2, %0" : "+v"(d) : "v"(a), "v"(w))

// ---- single-instruction DPP adds for the wave-64 sum ----
// (volatile + round-robin call order keeps dependent stages >=6 instrs apart,
//  covering the DPP read-after-VALU-write hazard by construction)
#define DPPADD_SHR(v, N) \
    asm volatile("v_add_f32_dpp %0, %0, %0 row_shr:" #N " row_mask:0xf bank_mask:0xf bound_ctrl:0" : "+v"(v))
#define DPPADD_BC15(v) \
    asm volatile("v_add_f32_dpp %0, %0, %0 row_bcast:15 row_mask:0xa bank_mask:0xf bound_ctrl:0" : "+v"(v))
#define DPPADD_BC31(v) \
    asm volatile("v_add_f32_dpp %0, %0, %0 row_bcast:31 row_mask:0xc bank_mask:0xf bound_ctrl:0" : "+v"(v))

#define LANE_SUM(v)  __int_as_float(__builtin_amdgcn_readlane(__float_as_int(v), 63))
#define RDLANE(v, l) __int_as_float(__builtin_amdgcn_readlane(__float_as_int(v), (l)))

// One wave per batch element b. Lane L owns hidden units j = u*64+L, u=0..3,
// for BOTH MLPs. Inputs for 64 steps staged per-lane, broadcast via readlane.
__global__ __launch_bounds__(256, 1)
void visco_kernel(const float* __restrict__ e,    const float* __restrict__ ed,
                  const float* __restrict__ Earr, const float* __restrict__ nuarr,
                  const float* __restrict__ We,   const float* __restrict__ be,
                  const float* __restrict__ Wn,   const float* __restrict__ bn,
                  const float* __restrict__ Wen1, const float* __restrict__ ben1,
                  const float* __restrict__ Wen2, const float* __restrict__ ben2,
                  const float* __restrict__ Wd1,  const float* __restrict__ bd1,
                  const float* __restrict__ Wd2,  const float* __restrict__ bd2,
                  float* __restrict__ out)
{
    const int lane = threadIdx.x & 63;
    const int wv   = threadIdx.x >> 6;
    const int b    = (blockIdx.x << 2) + wv;   // 2048 blocks * 4 waves = 8192

    // ---- per-lane weight registers (K-pair layout) ----
    v2f   wP[2][4][9];   // wP[m][u][kk] = (W1[2kk][j], W1[2kk+1][j])
    v2f   cstP[2][4];    // {bias + mf-fold, 0} — pk-fma seed
    float w2s[4];        // Wen2[j]
    float w2k[4][6];     // Wd2[j][i]

    const float Eb  = Earr[b];
    const float nub = nuarr[b];

    #pragma unroll
    for (int u = 0; u < 4; ++u) {
        const int j = (u << 6) + lane;
        #pragma unroll
        for (int kk = 0; kk < 9; ++kk) {
            wP[0][u][kk] = v2f{Wen1[(2 * kk) * HIDN + j], Wen1[(2 * kk + 1) * HIDN + j]};
            wP[1][u][kk] = v2f{Wd1 [(2 * kk) * HIDN + j], Wd1 [(2 * kk + 1) * HIDN + j]};
        }
        float c0 = ben1[j];
        float c1 = bd1[j];
        #pragma unroll
        for (int k = 0; k < 16; ++k) {           // mf[0:16] = E*We + be
            const float m = fmaf(Eb, We[k], be[k]);
            c0 = fmaf(m, Wen1[(18 + k) * HIDN + j], c0);
            c1 = fmaf(m, Wd1 [(18 + k) * HIDN + j], c1);
        }
        #pragma unroll
        for (int k = 0; k < 16; ++k) {           // mf[16:32] = nu*Wn + bn
            const float m = fmaf(nub, Wn[k], bn[k]);
            c0 = fmaf(m, Wen1[(34 + k) * HIDN + j], c0);
            c1 = fmaf(m, Wd1 [(34 + k) * HIDN + j], c1);
        }
        cstP[0][u] = v2f{c0, 0.f};
        cstP[1][u] = v2f{c1, 0.f};
        w2s[u] = Wen2[j];
        #pragma unroll
        for (int i = 0; i < 6; ++i) w2k[u][i] = Wd2[j * 6 + i];
    }

    const float ben2v = ben2[0];
    float bd2v[6];
    #pragma unroll
    for (int i = 0; i < 6; ++i) bd2v[i] = bd2[i];

    // ---- state (uniform across lanes) + output streams ----
    v2f xi01 = v2f{0.f, 0.f}, xi23 = v2f{0.f, 0.f}, xi45 = v2f{0.f, 0.f};

    const float* eb = e  + (size_t)b * (TN * 6);
    const float* db = ed + (size_t)b * (TN * 6);
    float* outS = out + (size_t)b * TN;                            // stress [B,T]
    float* outX = out + (size_t)BN * TN + (size_t)b * (TN * 6);    // xi_all [B,T,6]

    for (int half = 0; half < 2; ++half) {
        // stage 64 steps: lane L holds features of step (half*64 + L)
        float sE[6], sD[6];
        const int base = ((half << 6) + lane) * 6;
        #pragma unroll
        for (int r = 0; r < 6; ++r) { sE[r] = eb[base + r]; sD[r] = db[base + r]; }

        #pragma unroll 2
        for (int t2 = 0; t2 < 64; ++t2) {
            const int t = (half << 6) + t2;

            // broadcast step t's inputs from lane t2 (pure VALU, no memory)
            const v2f x0 = v2f{RDLANE(sE[0], t2), RDLANE(sE[1], t2)};
            const v2f x1 = v2f{RDLANE(sE[2], t2), RDLANE(sE[3], t2)};
            const v2f x2 = v2f{RDLANE(sE[4], t2), RDLANE(sE[5], t2)};
            const v2f x3 = v2f{RDLANE(sD[0], t2), RDLANE(sD[1], t2)};
            const v2f x4 = v2f{RDLANE(sD[2], t2), RDLANE(sD[3], t2)};
            const v2f x5 = v2f{RDLANE(sD[4], t2), RDLANE(sD[5], t2)};

            float ps  = 0.f;
            float pk0 = 0.f, pk1 = 0.f, pk2 = 0.f, pk3 = 0.f, pk4 = 0.f, pk5 = 0.f;

            #pragma unroll
            for (int u = 0; u < 4; ++u) {
                v2f hp, gp;
                PK_FMA3(hp, x0, wP[0][u][0], cstP[0][u]);   // seed from cst
                PK_FMA3(gp, x0, wP[1][u][0], cstP[1][u]);
                PK_FMA(hp, x1,   wP[0][u][1]);  PK_FMA(gp, x1,   wP[1][u][1]);
                PK_FMA(hp, x2,   wP[0][u][2]);  PK_FMA(gp, x2,   wP[1][u][2]);
                PK_FMA(hp, x3,   wP[0][u][3]);  PK_FMA(gp, x3,   wP[1][u][3]);
                PK_FMA(hp, x4,   wP[0][u][4]);  PK_FMA(gp, x4,   wP[1][u][4]);
                PK_FMA(hp, x5,   wP[0][u][5]);  PK_FMA(gp, x5,   wP[1][u][5]);
                PK_FMA(hp, xi01, wP[0][u][6]);  PK_FMA(gp, xi01, wP[1][u][6]);
                PK_FMA(hp, xi23, wP[0][u][7]);  PK_FMA(gp, xi23, wP[1][u][7]);
                PK_FMA(hp, xi45, wP[0][u][8]);  PK_FMA(gp, xi45, wP[1][u][8]);

                const float h = fmaxf(hp.x + hp.y, 0.f);
                const float g = fmaxf(gp.x + gp.y, 0.f);
                SFMA(ps,  h, w2s[u]);
                SFMA(pk0, g, w2k[u][0]);
                SFMA(pk1, g, w2k[u][1]);
                SFMA(pk2, g, w2k[u][2]);
                SFMA(pk3, g, w2k[u][3]);
                SFMA(pk4, g, w2k[u][4]);
                SFMA(pk5, g, w2k[u][5]);
            }

            // wave-64 sum: 6 DPP stages, round-robin over the 7 values
            DPPADD_SHR(ps, 1);  DPPADD_SHR(pk0, 1); DPPADD_SHR(pk1, 1);
            DPPADD_SHR(pk2, 1); DPPADD_SHR(pk3, 1); DPPADD_SHR(pk4, 1); DPPADD_SHR(pk5, 1);
            DPPADD_SHR(ps, 2);  DPPADD_SHR(pk0, 2); DPPADD_SHR(pk1, 2);
            DPPADD_SHR(pk2, 2); DPPADD_SHR(pk3, 2); DPPADD_SHR(pk4, 2); DPPADD_SHR(pk5, 2);
            DPPADD_SHR(ps, 4);  DPPADD_SHR(pk0, 4); DPPADD_SHR(pk1, 4);
            DPPADD_SHR(pk2, 4); DPPADD_SHR(pk3, 4); DPPADD_SHR(pk4, 4); DPPADD_SHR(pk5, 4);
            DPPADD_SHR(ps, 8);  DPPADD_SHR(pk0, 8); DPPADD_SHR(pk1, 8);
            DPPADD_SHR(pk2, 8); DPPADD_SHR(pk3, 8); DPPADD_SHR(pk4, 8); DPPADD_SHR(pk5, 8);
            DPPADD_BC15(ps);  DPPADD_BC15(pk0); DPPADD_BC15(pk1);
            DPPADD_BC15(pk2); DPPADD_BC15(pk3); DPPADD_BC15(pk4); DPPADD_BC15(pk5);
            DPPADD_BC31(ps);  DPPADD_BC31(pk0); DPPADD_BC31(pk1);
            DPPADD_BC31(pk2); DPPADD_BC31(pk3); DPPADD_BC31(pk4); DPPADD_BC31(pk5);

            const float sS = LANE_SUM(ps);
            const float s0 = LANE_SUM(pk0);
            const float s1 = LANE_SUM(pk1);
            const float s2 = LANE_SUM(pk2);
            const float s3 = LANE_SUM(pk3);
            const float s4 = LANE_SUM(pk4);
            const float s5 = LANE_SUM(pk5);

            // emit xi BEFORE update, stress
            const float xw = (lane == 0) ? xi01.x :
                             (lane == 1) ? xi01.y :
                             (lane == 2) ? xi23.x :
                             (lane == 3) ? xi23.y :
                             (lane == 4) ? xi45.x : xi45.y;
            if (lane < 6)  outX[t * 6 + lane] = xw;
            if (lane == 6) outS[t] = sS + ben2v;

            // explicit Euler: xi += DT * (kin_sum + bd2)   (reference order)
            xi01.x = fmaf(DTC, s0 + bd2v[0], xi01.x);
            xi01.y = fmaf(DTC, s1 + bd2v[1], xi01.y);
            xi23.x = fmaf(DTC, s2 + bd2v[2], xi23.x);
            xi23.y = fmaf(DTC, s3 + bd2v[3], xi23.y);
            xi45.x = fmaf(DTC, s4 + bd2v[4], xi45.x);
            xi45.y = fmaf(DTC, s5 + bd2v[5], xi45.y);
        }
    }
}

extern "C" void kernel_launch(void* const* d_in, const int* in_sizes, int n_in,
                              void* d_out, int out_size, void* d_ws, size_t ws_size,
                              hipStream_t stream) {
    const float* e    = (const float*)d_in[0];
    const float* ed   = (const float*)d_in[1];
    const float* E    = (const float*)d_in[2];
    const float* nu   = (const float*)d_in[3];
    const float* We   = (const float*)d_in[4];
    const float* be   = (const float*)d_in[5];
    const float* Wn   = (const float*)d_in[6];
    const float* bn   = (const float*)d_in[7];
    const float* Wen1 = (const float*)d_in[8];
    const float* ben1 = (const float*)d_in[9];
    const float* Wen2 = (const float*)d_in[10];
    const float* ben2 = (const float*)d_in[11];
    const float* Wd1  = (const float*)d_in[12];
    const float* bd1  = (const float*)d_in[13];
    const float* Wd2  = (const float*)d_in[14];
    const float* bd2  = (const float*)d_in[15];
    float* out = (float*)d_out;

    dim3 grid(BN / 4);   // 4 waves (4 batch elems) per 256-thread block
    dim3 block(256);
    visco_kernel<<<grid, block, 0, stream>>>(e, ed, E, nu, We, be, Wn, bn,
                                             Wen1, ben1, Wen2, ben2,
                                             Wd1, bd1, Wd2, bd2, out);
}